// Round 1
// baseline (655.049 us; speedup 1.0000x reference)
//
#include <hip/hip_runtime.h>
#include <stdint.h>

#define NB 4
#define SEQ 16384
#define CH 512
#define NH 16
#define HD 32
#define QKVC 1536
#define MROWS (NB * SEQ) /* 65536 */

typedef unsigned short u16;
typedef __attribute__((ext_vector_type(8))) short bf16x8;
typedef __attribute__((ext_vector_type(4))) float f32x4;

__device__ __forceinline__ float bf2f(u16 u) {
  union { unsigned int i; float f; } c; c.i = ((unsigned int)u) << 16; return c.f;
}
__device__ __forceinline__ u16 f2bf(float f) {
  union { float f; unsigned int i; } c; c.f = f;
  return (u16)((c.i + 0x7fffu + ((c.i >> 16) & 1u)) >> 16);
}

__device__ __forceinline__ void async16(const u16* g, u16* l) {
  __builtin_amdgcn_global_load_lds((const __attribute__((address_space(1))) void*)g,
                                   (__attribute__((address_space(3))) void*)l,
                                   16, 0, 0);
}

// ---------------------------------------------------------------------------
// Kernel 0: cast x / qkv_weight / proj_weight f32 -> bf16, zero vk accumulator
// ---------------------------------------------------------------------------
__global__ void prep_kernel(const float* __restrict__ x,
                            const float* __restrict__ qw,
                            const float* __restrict__ pw,
                            u16* __restrict__ xb,
                            u16* __restrict__ qwb,
                            u16* __restrict__ pwb,
                            float* __restrict__ vk) {
  int gid = blockIdx.x * blockDim.x + threadIdx.x;
  int stride = gridDim.x * blockDim.x;

  const float4* x4 = (const float4*)x;
  ushort4* xb4 = (ushort4*)xb;
  for (int i = gid; i < (MROWS * CH / 4); i += stride) {
    float4 v = x4[i];
    ushort4 o; o.x = f2bf(v.x); o.y = f2bf(v.y); o.z = f2bf(v.z); o.w = f2bf(v.w);
    xb4[i] = o;
  }
  const float4* q4 = (const float4*)qw;
  ushort4* qwb4 = (ushort4*)qwb;
  for (int i = gid; i < (QKVC * CH / 4); i += stride) {
    float4 v = q4[i];
    ushort4 o; o.x = f2bf(v.x); o.y = f2bf(v.y); o.z = f2bf(v.z); o.w = f2bf(v.w);
    qwb4[i] = o;
  }
  const float4* p4 = (const float4*)pw;
  ushort4* pwb4 = (ushort4*)pwb;
  for (int i = gid; i < (CH * CH / 4); i += stride) {
    float4 v = p4[i];
    ushort4 o; o.x = f2bf(v.x); o.y = f2bf(v.y); o.z = f2bf(v.z); o.w = f2bf(v.w);
    pwb4[i] = o;
  }
  float4 z; z.x = 0.f; z.y = 0.f; z.z = 0.f; z.w = 0.f;
  float4* vk4 = (float4*)vk;
  for (int i = gid; i < (NB * NH * 33 * 32 / 4); i += stride) vk4[i] = z;
}

// ---------------------------------------------------------------------------
// bf16 GEMM, C = A[M,K=512] * B^T where Bm is [N_DIM, 512] row-major.
// 128x128 tile, BK=32, 4 waves, each wave 64x64 (4x4 frags of 16x16x32 MFMA).
// RELU_QK: relu on output cols < 1024, bf16 out. FINAL: +bias, f32 out.
// ---------------------------------------------------------------------------
template <int N_DIM, bool RELU_QK, bool FINAL>
__global__ __launch_bounds__(256) void gemm_bt_kernel(
    const u16* __restrict__ A, const u16* __restrict__ Bm,
    void* __restrict__ Out, const float* __restrict__ bias) {
  constexpr int K = 512;
  __shared__ u16 As[128 * 32];
  __shared__ u16 Bs[128 * 32];

  const int tid = threadIdx.x;
  const int lane = tid & 63;
  const int w = tid >> 6;
  const long row0 = (long)blockIdx.y * 128;
  const int col0 = blockIdx.x * 128;

  const int l4r = lane >> 2;       // 0..15: row within 16-row staging group
  const int l4c = (lane & 3) * 8;  // element offset within row (8 bf16 = 16B)
  const int wr = w >> 1, wc = w & 1;
  const int fr = lane & 15;
  const int koff = (lane >> 4) * 8;

  f32x4 acc[4][4];
#pragma unroll
  for (int m = 0; m < 4; m++)
#pragma unroll
    for (int n = 0; n < 4; n++) {
      f32x4 z = {0.f, 0.f, 0.f, 0.f};
      acc[m][n] = z;
    }

  for (int k0 = 0; k0 < K; k0 += 32) {
#pragma unroll
    for (int i = 0; i < 2; i++) {
      const int r = w * 32 + i * 16;
      async16(A + (row0 + r + l4r) * K + k0 + l4c, &As[r * 32]);
      async16(Bm + (long)(col0 + r + l4r) * K + k0 + l4c, &Bs[r * 32]);
    }
    __syncthreads();
    bf16x8 af[4], bfr[4];
#pragma unroll
    for (int m = 0; m < 4; m++)
      af[m] = *(const bf16x8*)&As[(wr * 64 + m * 16 + fr) * 32 + koff];
#pragma unroll
    for (int n = 0; n < 4; n++)
      bfr[n] = *(const bf16x8*)&Bs[(wc * 64 + n * 16 + fr) * 32 + koff];
#pragma unroll
    for (int m = 0; m < 4; m++)
#pragma unroll
      for (int n = 0; n < 4; n++)
        acc[m][n] = __builtin_amdgcn_mfma_f32_16x16x32_bf16(af[m], bfr[n], acc[m][n], 0, 0, 0);
    __syncthreads();
  }

  const long rbase = row0 + wr * 64;
  const int cbase = col0 + wc * 64;
#pragma unroll
  for (int m = 0; m < 4; m++)
#pragma unroll
    for (int n = 0; n < 4; n++)
#pragma unroll
      for (int j = 0; j < 4; j++) {
        long gr = rbase + m * 16 + (lane >> 4) * 4 + j;
        int gc = cbase + n * 16 + fr;
        float v = acc[m][n][j];
        if constexpr (FINAL) {
          ((float*)Out)[gr * N_DIM + gc] = v + bias[gc];
        } else {
          if (RELU_QK && gc < 1024) v = fmaxf(v, 0.f);
          ((u16*)Out)[gr * N_DIM + gc] = f2bf(v);
        }
      }
}

// ---------------------------------------------------------------------------
// Kernel 2: vk[b,h,c,d] = sum_n v_pad[b,n,h,c] * k[b,n,h,d]   (c in 0..32)
// grid = B*H*SPLIT(16), block = 256 (32 lanes d x 8 n-groups), fp32 atomics.
// ---------------------------------------------------------------------------
__global__ __launch_bounds__(256) void vk_kernel(const u16* __restrict__ qkv,
                                                 float* __restrict__ vk) {
  const int bid = blockIdx.x;
  const int b = bid >> 8;
  const int h = (bid >> 4) & 15;
  const int s = bid & 15;
  const int tx = threadIdx.x & 31;
  const int ty = threadIdx.x >> 5;

  float acc[33];
#pragma unroll
  for (int c = 0; c < 33; c++) acc[c] = 0.f;

  const size_t base = (size_t)b * SEQ * QKVC + h * 32;
  const u16* kp = qkv + base + 512 + tx;
  const u16* vp = qkv + base + 1024 + tx;
  const int n0 = s * (SEQ / 16);

  for (int i = 0; i < (SEQ / 16) / 8; i++) {
    size_t off = (size_t)(n0 + i * 8 + ty) * QKVC;
    float kv = bf2f(kp[off]);
    float vv = bf2f(vp[off]);
#pragma unroll
    for (int c = 0; c < 32; c++) acc[c] = fmaf(__shfl(vv, c, 32), kv, acc[c]);
    acc[32] += kv;
  }

  __shared__ float lvk[33 * 32];
  for (int i = threadIdx.x; i < 33 * 32; i += 256) lvk[i] = 0.f;
  __syncthreads();
#pragma unroll
  for (int c = 0; c < 33; c++) atomicAdd(&lvk[c * 32 + tx], acc[c]);
  __syncthreads();
  float* dst = vk + (size_t)(b * NH + h) * (33 * 32);
  for (int i = threadIdx.x; i < 33 * 32; i += 256) atomicAdd(&dst[i], lvk[i]);
}

// ---------------------------------------------------------------------------
// Kernel 3: vk_q + divide -> proj_input (bf16).
// block = 512 threads: h = t>>5, c = t&31. vk rows held in registers.
// ---------------------------------------------------------------------------
__global__ __launch_bounds__(512) void vkq_kernel(const u16* __restrict__ qkv,
                                                  const float* __restrict__ vk,
                                                  u16* __restrict__ pi) {
  const int blocksPerB = SEQ / 64;
  const int b = blockIdx.x / blocksPerB;
  const int n0 = (blockIdx.x % blocksPerB) * 64;
  const int h = threadIdx.x >> 5;
  const int c = threadIdx.x & 31;

  const float* vkb = vk + (size_t)(b * NH + h) * (33 * 32);
  float wrow[32], nrow[32];
#pragma unroll
  for (int d = 0; d < 32; d++) {
    wrow[d] = vkb[c * 32 + d];
    nrow[d] = vkb[32 * 32 + d];
  }
  const u16* qb = qkv + (size_t)b * SEQ * QKVC + h * 32 + c;
  u16* pb = pi + (size_t)b * SEQ * CH + h * 32 + c;

  for (int r = 0; r < 64; r++) {
    size_t n = (size_t)(n0 + r);
    float qv = bf2f(qb[n * QKVC]);
    float num = 0.f, den = 0.f;
#pragma unroll
    for (int d = 0; d < 32; d++) {
      float qd = __shfl(qv, d, 32);
      num = fmaf(qd, wrow[d], num);
      den = fmaf(qd, nrow[d], den);
    }
    pb[n * CH] = f2bf(num / (den + 1e-15f));
  }
}

// ---------------------------------------------------------------------------
extern "C" void kernel_launch(void* const* d_in, const int* in_sizes, int n_in,
                              void* d_out, int out_size, void* d_ws, size_t ws_size,
                              hipStream_t stream) {
  const float* x = (const float*)d_in[0];
  const float* qw = (const float*)d_in[1];
  const float* pw = (const float*)d_in[2];
  const float* bias = (const float*)d_in[3];

  char* ws = (char*)d_ws;
  u16* qkv = (u16*)(ws);                      // 65536*1536*2 = 201326592 B
  u16* xb = (u16*)(ws + 201326592);           // 65536*512*2  =  67108864 B
  u16* qwb = (u16*)(ws + 268435456);          // 1536*512*2   =   1572864 B
  u16* pwb = (u16*)(ws + 270008320);          // 512*512*2    =    524288 B
  float* vk = (float*)(ws + 270532608);       // 64*1056*4    =    270336 B
  u16* pi = xb;  // alias: x_bf16 dead after QKV GEMM; reuse for proj_input

  prep_kernel<<<2048, 256, 0, stream>>>(x, qw, pw, xb, qwb, pwb, vk);
  gemm_bt_kernel<QKVC, true, false>
      <<<dim3(QKVC / 128, MROWS / 128), 256, 0, stream>>>(xb, qwb, qkv, nullptr);
  vk_kernel<<<NB * NH * 16, 256, 0, stream>>>(qkv, vk);
  vkq_kernel<<<NB * (SEQ / 64), 512, 0, stream>>>(qkv, vk, pi);
  gemm_bt_kernel<CH, false, true>
      <<<dim3(CH / 128, MROWS / 128), 256, 0, stream>>>(pi, pwb, d_out, bias);
}

// Round 2
// 360.779 us; speedup vs baseline: 1.8156x; 1.8156x over previous
//
#include <hip/hip_runtime.h>
#include <stdint.h>

#define NB 4
#define SEQ 16384
#define CH 512
#define NH 16
#define HD 32
#define QKVC 1536
#define MROWS (NB * SEQ) /* 65536 */

typedef unsigned short u16;
typedef __attribute__((ext_vector_type(8))) short bf16x8;
typedef __attribute__((ext_vector_type(4))) float f32x4;

__device__ __forceinline__ float bf2f(u16 u) {
  union { unsigned int i; float f; } c; c.i = ((unsigned int)u) << 16; return c.f;
}
__device__ __forceinline__ u16 f2bf(float f) {
  union { float f; unsigned int i; } c; c.f = f;
  return (u16)((c.i + 0x7fffu + ((c.i >> 16) & 1u)) >> 16);
}

__device__ __forceinline__ void async16(const u16* g, u16* l) {
  __builtin_amdgcn_global_load_lds((const __attribute__((address_space(1))) void*)g,
                                   (__attribute__((address_space(3))) void*)l,
                                   16, 0, 0);
}

// ---------------------------------------------------------------------------
// Kernel 0: cast x / qkv_weight / proj_weight f32 -> bf16, zero vk accumulator
// ---------------------------------------------------------------------------
__global__ void prep_kernel(const float* __restrict__ x,
                            const float* __restrict__ qw,
                            const float* __restrict__ pw,
                            u16* __restrict__ xb,
                            u16* __restrict__ qwb,
                            u16* __restrict__ pwb,
                            float* __restrict__ vk) {
  int gid = blockIdx.x * blockDim.x + threadIdx.x;
  int stride = gridDim.x * blockDim.x;

  const float4* x4 = (const float4*)x;
  ushort4* xb4 = (ushort4*)xb;
  for (int i = gid; i < (MROWS * CH / 4); i += stride) {
    float4 v = x4[i];
    ushort4 o; o.x = f2bf(v.x); o.y = f2bf(v.y); o.z = f2bf(v.z); o.w = f2bf(v.w);
    xb4[i] = o;
  }
  const float4* q4 = (const float4*)qw;
  ushort4* qwb4 = (ushort4*)qwb;
  for (int i = gid; i < (QKVC * CH / 4); i += stride) {
    float4 v = q4[i];
    ushort4 o; o.x = f2bf(v.x); o.y = f2bf(v.y); o.z = f2bf(v.z); o.w = f2bf(v.w);
    qwb4[i] = o;
  }
  const float4* p4 = (const float4*)pw;
  ushort4* pwb4 = (ushort4*)pwb;
  for (int i = gid; i < (CH * CH / 4); i += stride) {
    float4 v = p4[i];
    ushort4 o; o.x = f2bf(v.x); o.y = f2bf(v.y); o.z = f2bf(v.z); o.w = f2bf(v.w);
    pwb4[i] = o;
  }
  float4 z; z.x = 0.f; z.y = 0.f; z.z = 0.f; z.w = 0.f;
  float4* vk4 = (float4*)vk;
  for (int i = gid; i < (NB * NH * 33 * 32 / 4); i += stride) vk4[i] = z;
}

// ---------------------------------------------------------------------------
// bf16 GEMM, C = A[M,K=512] * B^T where Bm is [N_DIM, 512] row-major.
// 128x128 tile, BK=32, 4 waves, each wave 64x64 (4x4 frags of 16x16x32 MFMA).
// RELU_QK: relu on output cols < 1024, bf16 out. FINAL: +bias, f32 out.
// ---------------------------------------------------------------------------
template <int N_DIM, bool RELU_QK, bool FINAL>
__global__ __launch_bounds__(256) void gemm_bt_kernel(
    const u16* __restrict__ A, const u16* __restrict__ Bm,
    void* __restrict__ Out, const float* __restrict__ bias) {
  constexpr int K = 512;
  __shared__ u16 As[128 * 32];
  __shared__ u16 Bs[128 * 32];

  const int tid = threadIdx.x;
  const int lane = tid & 63;
  const int w = tid >> 6;
  const long row0 = (long)blockIdx.y * 128;
  const int col0 = blockIdx.x * 128;

  const int l4r = lane >> 2;       // 0..15: row within 16-row staging group
  const int l4c = (lane & 3) * 8;  // element offset within row (8 bf16 = 16B)
  const int wr = w >> 1, wc = w & 1;
  const int fr = lane & 15;
  const int koff = (lane >> 4) * 8;

  f32x4 acc[4][4];
#pragma unroll
  for (int m = 0; m < 4; m++)
#pragma unroll
    for (int n = 0; n < 4; n++) {
      f32x4 z = {0.f, 0.f, 0.f, 0.f};
      acc[m][n] = z;
    }

  for (int k0 = 0; k0 < K; k0 += 32) {
#pragma unroll
    for (int i = 0; i < 2; i++) {
      const int r = w * 32 + i * 16;
      async16(A + (row0 + r + l4r) * K + k0 + l4c, &As[r * 32]);
      async16(Bm + (long)(col0 + r + l4r) * K + k0 + l4c, &Bs[r * 32]);
    }
    __syncthreads();
    bf16x8 af[4], bfr[4];
#pragma unroll
    for (int m = 0; m < 4; m++)
      af[m] = *(const bf16x8*)&As[(wr * 64 + m * 16 + fr) * 32 + koff];
#pragma unroll
    for (int n = 0; n < 4; n++)
      bfr[n] = *(const bf16x8*)&Bs[(wc * 64 + n * 16 + fr) * 32 + koff];
#pragma unroll
    for (int m = 0; m < 4; m++)
#pragma unroll
      for (int n = 0; n < 4; n++)
        acc[m][n] = __builtin_amdgcn_mfma_f32_16x16x32_bf16(af[m], bfr[n], acc[m][n], 0, 0, 0);
    __syncthreads();
  }

  const long rbase = row0 + wr * 64;
  const int cbase = col0 + wc * 64;
#pragma unroll
  for (int m = 0; m < 4; m++)
#pragma unroll
    for (int n = 0; n < 4; n++)
#pragma unroll
      for (int j = 0; j < 4; j++) {
        long gr = rbase + m * 16 + (lane >> 4) * 4 + j;
        int gc = cbase + n * 16 + fr;
        float v = acc[m][n][j];
        if constexpr (FINAL) {
          ((float*)Out)[gr * N_DIM + gc] = v + bias[gc];
        } else {
          if (RELU_QK && gc < 1024) v = fmaxf(v, 0.f);
          ((u16*)Out)[gr * N_DIM + gc] = f2bf(v);
        }
      }
}

// ---------------------------------------------------------------------------
// Kernel 2 (MFMA): vk[b,h,c,d] = sum_n v[n,h,c]*k[n,h,d], row 32 = sum_n k.
// Grid = 64 (b,h) x 16 splits. 4 waves/block, each wave owns a private
// 64x64 LDS tile (cols 0-31 = k, 32-63 = v) staged via global_load_lds.
// A = v (c rows), B = k (d cols); ones-A MFMA gives the normalizer row.
// ---------------------------------------------------------------------------
__global__ __launch_bounds__(256) void vk_kernel(const u16* __restrict__ qkv,
                                                 float* __restrict__ vk) {
  __shared__ u16 tile[4][64 * 64];   // 32 KB
  __shared__ float red[1056];        // 4.2 KB block accumulator

  const int tid = threadIdx.x;
  const int lane = tid & 63;
  const int w = tid >> 6;

  for (int i = tid; i < 1056; i += 256) red[i] = 0.f;
  __syncthreads();

  const int bh = blockIdx.x >> 4;
  const int split = blockIdx.x & 15;
  const int b = bh >> 4, h = bh & 15;

  const int s = lane & 7;   // column segment: 0-3 -> k, 4-7 -> v
  const int rl = lane >> 3; // row within 8-row staging group
  const size_t gbase = (size_t)b * SEQ * QKVC + 512 + (size_t)(s >> 2) * 512 +
                       h * 32 + (s & 3) * 8;

  f32x4 acc[2][2];
  f32x4 accs[2];
#pragma unroll
  for (int tc = 0; tc < 2; tc++) {
    f32x4 z = {0.f, 0.f, 0.f, 0.f};
    accs[tc] = z;
#pragma unroll
    for (int td = 0; td < 2; td++) acc[tc][td] = z;
  }
  bf16x8 ones;
#pragma unroll
  for (int j = 0; j < 8; j++) ones[j] = (short)0x3F80;  // bf16 1.0

  const int m = lane & 15;
  const int g = lane >> 4;
  u16* tw = tile[w];
  const int n0w = split * 1024 + w * 256;

  for (int t = 0; t < 4; ++t) {
    const int nt = n0w + t * 64;
#pragma unroll
    for (int p = 0; p < 8; ++p)
      async16(qkv + gbase + (size_t)(nt + p * 8 + rl) * QKVC, &tw[p * 512]);
    asm volatile("s_waitcnt vmcnt(0)" ::: "memory");
#pragma unroll
    for (int kk = 0; kk < 2; ++kk) {
      bf16x8 av[2], bk[2];
#pragma unroll
      for (int tc = 0; tc < 2; tc++)
#pragma unroll
        for (int j = 0; j < 8; j++)
          av[tc][j] = (short)tw[(kk * 32 + g * 8 + j) * 64 + 32 + tc * 16 + m];
#pragma unroll
      for (int td = 0; td < 2; td++)
#pragma unroll
        for (int j = 0; j < 8; j++)
          bk[td][j] = (short)tw[(kk * 32 + g * 8 + j) * 64 + td * 16 + m];
#pragma unroll
      for (int tc = 0; tc < 2; tc++)
#pragma unroll
        for (int td = 0; td < 2; td++)
          acc[tc][td] = __builtin_amdgcn_mfma_f32_16x16x32_bf16(av[tc], bk[td], acc[tc][td], 0, 0, 0);
#pragma unroll
      for (int td = 0; td < 2; td++)
        accs[td] = __builtin_amdgcn_mfma_f32_16x16x32_bf16(ones, bk[td], accs[td], 0, 0, 0);
    }
  }

  // wave -> block reduction in LDS
#pragma unroll
  for (int tc = 0; tc < 2; tc++)
#pragma unroll
    for (int td = 0; td < 2; td++)
#pragma unroll
      for (int j = 0; j < 4; j++)
        atomicAdd(&red[(tc * 16 + g * 4 + j) * 32 + td * 16 + m], acc[tc][td][j]);
  if (lane < 16) {
#pragma unroll
    for (int td = 0; td < 2; td++)
      atomicAdd(&red[1024 + td * 16 + lane], accs[td][0]);  // all rows equal
  }
  __syncthreads();
  float* dst = vk + (size_t)bh * 1056;
  for (int i = tid; i < 1056; i += 256) atomicAdd(&dst[i], red[i]);
}

// ---------------------------------------------------------------------------
// Kernel 3 (shuffle-free): vk_q + divide -> proj_input (bf16).
// Block = 256: thread owns one (n, h) pair; 32 n x 8 h per block.
// vk (8 heads, fp32) staged in LDS; broadcast ds_read_b128; LDS bounce
// for coalesced 512-B output writes.
// ---------------------------------------------------------------------------
__global__ __launch_bounds__(256) void vkq_kernel(const u16* __restrict__ qkv,
                                                  const float* __restrict__ vk,
                                                  u16* __restrict__ pi) {
  __shared__ float vkl[8 * 1056];  // 33.8 KB
  __shared__ u16 ob[32 * 256];     // 16 KB output bounce

  const int tid = threadIdx.x;
  const int chunk = blockIdx.x & 511;
  const int hh = (blockIdx.x >> 9) & 1;
  const int b = blockIdx.x >> 10;
  const int n0 = chunk * 32;

  const float* vg = vk + (size_t)(b * NH + hh * 8) * 1056;
  for (int i = tid; i < 8 * 1056; i += 256) vkl[i] = vg[i];
  __syncthreads();

  const int nl = tid & 31;
  const int hl = tid >> 5;
  const float* vkh = &vkl[hl * 1056];

  const u16* qp = qkv + ((size_t)b * SEQ + n0 + nl) * QKVC + (hh * 8 + hl) * 32;
  float qf[32];
#pragma unroll
  for (int s2 = 0; s2 < 4; ++s2) {
    bf16x8 qv = *(const bf16x8*)(qp + s2 * 8);
#pragma unroll
    for (int j = 0; j < 8; ++j) qf[s2 * 8 + j] = bf2f((u16)qv[j]);
  }

  float num[32];
#pragma unroll
  for (int c = 0; c < 32; ++c) {
    float a = 0.f;
#pragma unroll
    for (int d4 = 0; d4 < 8; ++d4) {
      f32x4 vv = *(const f32x4*)&vkh[c * 32 + d4 * 4];
      a = fmaf(qf[d4 * 4 + 0], vv[0], a);
      a = fmaf(qf[d4 * 4 + 1], vv[1], a);
      a = fmaf(qf[d4 * 4 + 2], vv[2], a);
      a = fmaf(qf[d4 * 4 + 3], vv[3], a);
    }
    num[c] = a;
  }
  float den = 0.f;
#pragma unroll
  for (int d4 = 0; d4 < 8; ++d4) {
    f32x4 vv = *(const f32x4*)&vkh[32 * 32 + d4 * 4];
    den = fmaf(qf[d4 * 4 + 0], vv[0], den);
    den = fmaf(qf[d4 * 4 + 1], vv[1], den);
    den = fmaf(qf[d4 * 4 + 2], vv[2], den);
    den = fmaf(qf[d4 * 4 + 3], vv[3], den);
  }
  const float r = 1.0f / (den + 1e-15f);
#pragma unroll
  for (int c = 0; c < 32; ++c) ob[nl * 256 + hl * 32 + c] = f2bf(num[c] * r);
  __syncthreads();

  u16* pg = pi + ((size_t)b * SEQ + n0) * CH + hh * 256;
  for (int i = tid; i < 1024; i += 256) {  // 16-byte units
    const int n = i >> 5;
    const int u = i & 31;
    *(bf16x8*)(pg + (size_t)n * CH + u * 8) = *(const bf16x8*)&ob[i * 8];
  }
}

// ---------------------------------------------------------------------------
extern "C" void kernel_launch(void* const* d_in, const int* in_sizes, int n_in,
                              void* d_out, int out_size, void* d_ws, size_t ws_size,
                              hipStream_t stream) {
  const float* x = (const float*)d_in[0];
  const float* qw = (const float*)d_in[1];
  const float* pw = (const float*)d_in[2];
  const float* bias = (const float*)d_in[3];

  char* ws = (char*)d_ws;
  u16* qkv = (u16*)(ws);                      // 65536*1536*2 = 201326592 B
  u16* xb = (u16*)(ws + 201326592);           // 65536*512*2  =  67108864 B
  u16* qwb = (u16*)(ws + 268435456);          // 1536*512*2   =   1572864 B
  u16* pwb = (u16*)(ws + 270008320);          // 512*512*2    =    524288 B
  float* vk = (float*)(ws + 270532608);       // 64*1056*4    =    270336 B
  u16* pi = xb;  // alias: x_bf16 dead after QKV GEMM; reuse for proj_input

  prep_kernel<<<2048, 256, 0, stream>>>(x, qw, pw, xb, qwb, pwb, vk);
  gemm_bt_kernel<QKVC, true, false>
      <<<dim3(QKVC / 128, MROWS / 128), 256, 0, stream>>>(xb, qwb, qkv, nullptr);
  vk_kernel<<<NB * NH * 16, 256, 0, stream>>>(qkv, vk);
  vkq_kernel<<<NB * 2 * (SEQ / 32), 256, 0, stream>>>(qkv, vk, pi);
  gemm_bt_kernel<CH, false, true>
      <<<dim3(CH / 128, MROWS / 128), 256, 0, stream>>>(pi, pwb, d_out, bias);
}

// Round 3
// 319.371 us; speedup vs baseline: 2.0511x; 1.1297x over previous
//
#include <hip/hip_runtime.h>
#include <stdint.h>

#define NB 4
#define SEQ 16384
#define CH 512
#define NH 16
#define HD 32
#define QKVC 1536
#define MROWS (NB * SEQ) /* 65536 */

typedef unsigned short u16;
typedef __attribute__((ext_vector_type(8))) short bf16x8;
typedef __attribute__((ext_vector_type(4))) float f32x4;

__device__ __forceinline__ float bf2f(u16 u) {
  union { unsigned int i; float f; } c; c.i = ((unsigned int)u) << 16; return c.f;
}
__device__ __forceinline__ u16 f2bf(float f) {
  union { float f; unsigned int i; } c; c.f = f;
  return (u16)((c.i + 0x7fffu + ((c.i >> 16) & 1u)) >> 16);
}

__device__ __forceinline__ void async16(const u16* g, u16* l) {
  __builtin_amdgcn_global_load_lds((const __attribute__((address_space(1))) void*)g,
                                   (__attribute__((address_space(3))) void*)l,
                                   16, 0, 0);
}

// ---------------------------------------------------------------------------
// Kernel 0: cast x / qkv_weight / proj_weight f32 -> bf16, zero vk accumulator
// ---------------------------------------------------------------------------
__global__ void prep_kernel(const float* __restrict__ x,
                            const float* __restrict__ qw,
                            const float* __restrict__ pw,
                            u16* __restrict__ xb,
                            u16* __restrict__ qwb,
                            u16* __restrict__ pwb,
                            float* __restrict__ vk) {
  int gid = blockIdx.x * blockDim.x + threadIdx.x;
  int stride = gridDim.x * blockDim.x;

  const float4* x4 = (const float4*)x;
  ushort4* xb4 = (ushort4*)xb;
  for (int i = gid; i < (MROWS * CH / 4); i += stride) {
    float4 v = x4[i];
    ushort4 o; o.x = f2bf(v.x); o.y = f2bf(v.y); o.z = f2bf(v.z); o.w = f2bf(v.w);
    xb4[i] = o;
  }
  const float4* q4 = (const float4*)qw;
  ushort4* qwb4 = (ushort4*)qwb;
  for (int i = gid; i < (QKVC * CH / 4); i += stride) {
    float4 v = q4[i];
    ushort4 o; o.x = f2bf(v.x); o.y = f2bf(v.y); o.z = f2bf(v.z); o.w = f2bf(v.w);
    qwb4[i] = o;
  }
  const float4* p4 = (const float4*)pw;
  ushort4* pwb4 = (ushort4*)pwb;
  for (int i = gid; i < (CH * CH / 4); i += stride) {
    float4 v = p4[i];
    ushort4 o; o.x = f2bf(v.x); o.y = f2bf(v.y); o.z = f2bf(v.z); o.w = f2bf(v.w);
    pwb4[i] = o;
  }
  float4 z; z.x = 0.f; z.y = 0.f; z.z = 0.f; z.w = 0.f;
  float4* vk4 = (float4*)vk;
  for (int i = gid; i < (NB * NH * 33 * 32 / 4); i += stride) vk4[i] = z;
}

// ---------------------------------------------------------------------------
// 8-phase 256x256 bf16 GEMM (HK-style schedule in plain HIP).
// C = A[M,512] * B^T, Bm is [N_DIM,512] row-major. BK=64, 8 waves (2Mx4N),
// per-wave 128x64 output (8x4 frags of 16x16x32). LDS 128 KiB: per buf,
// A/B tiles split in 2 half-tiles of 128x64. XOR-swizzled LDS (both sides:
// pre-swizzled global source for global_load_lds + swizzled ds_read).
// Counted vmcnt(4) once per K-tile; raw s_barrier; setprio around MFMA.
// ---------------------------------------------------------------------------
template <int N_DIM, bool RELU_QK, bool FINAL>
__global__ __launch_bounds__(512, 2) void gemm8p_kernel(
    const u16* __restrict__ A, const u16* __restrict__ Bm,
    void* __restrict__ Out, const float* __restrict__ bias) {
  __shared__ __align__(16) u16 lds[65536];  // 128 KiB

  const int tid = threadIdx.x;
  const int lane = tid & 63;
  const int w = tid >> 6;   // 0..7
  const int wr = w >> 2;    // 0..1  (M half)
  const int wc = w & 3;     // 0..3  (N quarter)
  const int fr = lane & 15;
  const int g = lane >> 4;
  const int xr = (fr & 7) << 3;  // read-side XOR (u16 units)

  // XCD-bijective block swizzle (nwg % 8 == 0 for both shapes)
  const int gridX = N_DIM / 256;
  const int nwg = gridX * (MROWS / 256);
  int bid = blockIdx.y * gridX + blockIdx.x;
  bid = (bid & 7) * (nwg >> 3) + (bid >> 3);
  const long row0 = (long)(bid / gridX) * 256;
  const long col0 = (long)(bid % gridX) * 256;

  // staging constants: thread t stages LDS u16 slot j*4096 + t*8 of a half-tile;
  // source element pre-swizzled so swizzled read returns linear data.
  const int trow = tid >> 3;                                        // 0..63
  const int tcol = ((tid & 7) * 8) ^ (((tid >> 3) & 7) << 3);       // u16 units

#define STAGE_A(kt_, h_)                                                      \
  do {                                                                        \
    u16* lb_ = &lds[(((kt_) & 1) * 2 + (h_)) * 8192 + w * 512];               \
    const u16* ga_ = A + (size_t)(row0 + (h_) * 128 + trow) * 512 +           \
                     (kt_) * 64 + tcol;                                       \
    async16(ga_, lb_);                                                        \
    async16(ga_ + 64 * 512, lb_ + 4096);                                      \
  } while (0)

#define STAGE_B(kt_, h_)                                                      \
  do {                                                                        \
    u16* lb_ = &lds[32768 + (((kt_) & 1) * 2 + (h_)) * 8192 + w * 512];       \
    const u16* gb_ = Bm + (size_t)(col0 + (h_) * 128 + trow) * 512 +          \
                     (kt_) * 64 + tcol;                                       \
    async16(gb_, lb_);                                                        \
    async16(gb_ + 64 * 512, lb_ + 4096);                                      \
  } while (0)

  f32x4 acc[8][4];
#pragma unroll
  for (int m = 0; m < 8; m++)
#pragma unroll
    for (int n = 0; n < 4; n++) {
      f32x4 z = {0.f, 0.f, 0.f, 0.f};
      acc[m][n] = z;
    }
  bf16x8 a[4][2], b[4][2];

  // prologue: stage B0(0),A0(0),B1(0),A1(0),B0(1),A0(1); gate first 4.
  STAGE_B(0, 0); STAGE_A(0, 0); STAGE_B(0, 1); STAGE_A(0, 1);
  STAGE_B(1, 0); STAGE_A(1, 0);
  asm volatile("s_waitcnt vmcnt(4)" ::: "memory");
  __builtin_amdgcn_s_barrier();

#pragma unroll
  for (int kt = 0; kt < 8; ++kt) {
    const int abase = ((kt & 1) * 2 + wr) * 8192;
    const int bbase = 32768 + ((kt & 1) * 2 + (wc >> 1)) * 8192 + (wc & 1) * 4096;

    // ---- phase 0: read A m0-3 + B n0-1; stage B1(kt+1); MFMA q(m0-3,n0-1)
#pragma unroll
    for (int m = 0; m < 4; ++m)
#pragma unroll
      for (int kk = 0; kk < 2; ++kk)
        a[m][kk] = *(const bf16x8*)&lds[abase + (m * 16 + fr) * 64 + ((kk * 32 + g * 8) ^ xr)];
#pragma unroll
    for (int n = 0; n < 2; ++n)
#pragma unroll
      for (int kk = 0; kk < 2; ++kk)
        b[n][kk] = *(const bf16x8*)&lds[bbase + (n * 16 + fr) * 64 + ((kk * 32 + g * 8) ^ xr)];
    if (kt < 7) STAGE_B(kt + 1, 1);
    __builtin_amdgcn_s_barrier();
    asm volatile("s_waitcnt lgkmcnt(0)" ::: "memory");
    __builtin_amdgcn_s_setprio(1);
#pragma unroll
    for (int m = 0; m < 4; ++m)
#pragma unroll
      for (int n = 0; n < 2; ++n)
#pragma unroll
        for (int kk = 0; kk < 2; ++kk)
          acc[m][n] = __builtin_amdgcn_mfma_f32_16x16x32_bf16(a[m][kk], b[n][kk], acc[m][n], 0, 0, 0);
    __builtin_amdgcn_s_setprio(0);
    __builtin_amdgcn_s_barrier();

    // ---- phase 1: read B n2-3; stage A1(kt+1); MFMA q(m0-3,n2-3)
#pragma unroll
    for (int n = 0; n < 2; ++n)
#pragma unroll
      for (int kk = 0; kk < 2; ++kk)
        b[2 + n][kk] = *(const bf16x8*)&lds[bbase + ((n + 2) * 16 + fr) * 64 + ((kk * 32 + g * 8) ^ xr)];
    if (kt < 7) STAGE_A(kt + 1, 1);
    __builtin_amdgcn_s_barrier();
    asm volatile("s_waitcnt lgkmcnt(0)" ::: "memory");
    __builtin_amdgcn_s_setprio(1);
#pragma unroll
    for (int m = 0; m < 4; ++m)
#pragma unroll
      for (int n = 0; n < 2; ++n)
#pragma unroll
        for (int kk = 0; kk < 2; ++kk)
          acc[m][2 + n] = __builtin_amdgcn_mfma_f32_16x16x32_bf16(a[m][kk], b[2 + n][kk], acc[m][2 + n], 0, 0, 0);
    __builtin_amdgcn_s_setprio(0);
    __builtin_amdgcn_s_barrier();

    // ---- phase 2: read A m4-7 (reuse regs); stage B0(kt+2); MFMA q(m4-7,n2-3)
#pragma unroll
    for (int m = 0; m < 4; ++m)
#pragma unroll
      for (int kk = 0; kk < 2; ++kk)
        a[m][kk] = *(const bf16x8*)&lds[abase + ((m + 4) * 16 + fr) * 64 + ((kk * 32 + g * 8) ^ xr)];
    if (kt < 6) STAGE_B(kt + 2, 0);
    __builtin_amdgcn_s_barrier();
    asm volatile("s_waitcnt lgkmcnt(0)" ::: "memory");
    __builtin_amdgcn_s_setprio(1);
#pragma unroll
    for (int m = 0; m < 4; ++m)
#pragma unroll
      for (int n = 0; n < 2; ++n)
#pragma unroll
        for (int kk = 0; kk < 2; ++kk)
          acc[4 + m][2 + n] = __builtin_amdgcn_mfma_f32_16x16x32_bf16(a[m][kk], b[2 + n][kk], acc[4 + m][2 + n], 0, 0, 0);
    __builtin_amdgcn_s_setprio(0);
    __builtin_amdgcn_s_barrier();

    // ---- phase 3: stage A0(kt+2); counted vmcnt gate; MFMA q(m4-7,n0-1)
    if (kt < 6) {
      STAGE_A(kt + 2, 0);
      asm volatile("s_waitcnt vmcnt(4)" ::: "memory");
    } else {
      asm volatile("s_waitcnt vmcnt(0)" ::: "memory");
    }
    __builtin_amdgcn_s_barrier();
    __builtin_amdgcn_s_setprio(1);
#pragma unroll
    for (int m = 0; m < 4; ++m)
#pragma unroll
      for (int n = 0; n < 2; ++n)
#pragma unroll
        for (int kk = 0; kk < 2; ++kk)
          acc[4 + m][n] = __builtin_amdgcn_mfma_f32_16x16x32_bf16(a[m][kk], b[n][kk], acc[4 + m][n], 0, 0, 0);
    __builtin_amdgcn_s_setprio(0);
    __builtin_amdgcn_s_barrier();
  }
#undef STAGE_A
#undef STAGE_B

  // epilogue: C write. rows row0 + wr*128 + m*16 + g*4 + j, cols col0 + wc*64 + n*16 + fr
  const long rbase = row0 + wr * 128;
  const long cbase = col0 + wc * 64;
#pragma unroll
  for (int m = 0; m < 8; ++m)
#pragma unroll
    for (int n = 0; n < 4; ++n)
#pragma unroll
      for (int j = 0; j < 4; ++j) {
        long gr = rbase + m * 16 + g * 4 + j;
        long gc = cbase + n * 16 + fr;
        float v = acc[m][n][j];
        if constexpr (FINAL) {
          ((float*)Out)[gr * N_DIM + gc] = v + bias[gc];
        } else {
          if (RELU_QK && gc < 1024) v = fmaxf(v, 0.f);
          ((u16*)Out)[gr * N_DIM + gc] = f2bf(v);
        }
      }
}

// ---------------------------------------------------------------------------
// Kernel 2 (MFMA): vk[b,h,c,d] = sum_n v[n,h,c]*k[n,h,d], row 32 = sum_n k.
// ---------------------------------------------------------------------------
__global__ __launch_bounds__(256) void vk_kernel(const u16* __restrict__ qkv,
                                                 float* __restrict__ vk) {
  __shared__ u16 tile[4][64 * 64];   // 32 KB
  __shared__ float red[1056];        // 4.2 KB block accumulator

  const int tid = threadIdx.x;
  const int lane = tid & 63;
  const int w = tid >> 6;

  for (int i = tid; i < 1056; i += 256) red[i] = 0.f;
  __syncthreads();

  const int bh = blockIdx.x >> 4;
  const int split = blockIdx.x & 15;
  const int b = bh >> 4, h = bh & 15;

  const int s = lane & 7;   // column segment: 0-3 -> k, 4-7 -> v
  const int rl = lane >> 3; // row within 8-row staging group
  const size_t gbase = (size_t)b * SEQ * QKVC + 512 + (size_t)(s >> 2) * 512 +
                       h * 32 + (s & 3) * 8;

  f32x4 acc[2][2];
  f32x4 accs[2];
#pragma unroll
  for (int tc = 0; tc < 2; tc++) {
    f32x4 z = {0.f, 0.f, 0.f, 0.f};
    accs[tc] = z;
#pragma unroll
    for (int td = 0; td < 2; td++) acc[tc][td] = z;
  }
  bf16x8 ones;
#pragma unroll
  for (int j = 0; j < 8; j++) ones[j] = (short)0x3F80;  // bf16 1.0

  const int m = lane & 15;
  const int g = lane >> 4;
  u16* tw = tile[w];
  const int n0w = split * 1024 + w * 256;

  for (int t = 0; t < 4; ++t) {
    const int nt = n0w + t * 64;
#pragma unroll
    for (int p = 0; p < 8; ++p)
      async16(qkv + gbase + (size_t)(nt + p * 8 + rl) * QKVC, &tw[p * 512]);
    asm volatile("s_waitcnt vmcnt(0)" ::: "memory");
#pragma unroll
    for (int kk = 0; kk < 2; ++kk) {
      bf16x8 av[2], bk[2];
#pragma unroll
      for (int tc = 0; tc < 2; tc++)
#pragma unroll
        for (int j = 0; j < 8; j++)
          av[tc][j] = (short)tw[(kk * 32 + g * 8 + j) * 64 + 32 + tc * 16 + m];
#pragma unroll
      for (int td = 0; td < 2; td++)
#pragma unroll
        for (int j = 0; j < 8; j++)
          bk[td][j] = (short)tw[(kk * 32 + g * 8 + j) * 64 + td * 16 + m];
#pragma unroll
      for (int tc = 0; tc < 2; tc++)
#pragma unroll
        for (int td = 0; td < 2; td++)
          acc[tc][td] = __builtin_amdgcn_mfma_f32_16x16x32_bf16(av[tc], bk[td], acc[tc][td], 0, 0, 0);
#pragma unroll
      for (int td = 0; td < 2; td++)
        accs[td] = __builtin_amdgcn_mfma_f32_16x16x32_bf16(ones, bk[td], accs[td], 0, 0, 0);
    }
  }

#pragma unroll
  for (int tc = 0; tc < 2; tc++)
#pragma unroll
    for (int td = 0; td < 2; td++)
#pragma unroll
      for (int j = 0; j < 4; j++)
        atomicAdd(&red[(tc * 16 + g * 4 + j) * 32 + td * 16 + m], acc[tc][td][j]);
  if (lane < 16) {
#pragma unroll
    for (int td = 0; td < 2; td++)
      atomicAdd(&red[1024 + td * 16 + lane], accs[td][0]);
  }
  __syncthreads();
  float* dst = vk + (size_t)bh * 1056;
  for (int i = tid; i < 1056; i += 256) atomicAdd(&dst[i], red[i]);
}

// ---------------------------------------------------------------------------
// Kernel 3: vk_q + divide -> proj_input (bf16). Thread owns one (n,h) pair.
// ---------------------------------------------------------------------------
__global__ __launch_bounds__(256) void vkq_kernel(const u16* __restrict__ qkv,
                                                  const float* __restrict__ vk,
                                                  u16* __restrict__ pi) {
  __shared__ float vkl[8 * 1056];  // 33.8 KB
  __shared__ u16 ob[32 * 256];     // 16 KB output bounce

  const int tid = threadIdx.x;
  const int chunk = blockIdx.x & 511;
  const int hh = (blockIdx.x >> 9) & 1;
  const int b = blockIdx.x >> 10;
  const int n0 = chunk * 32;

  const float* vg = vk + (size_t)(b * NH + hh * 8) * 1056;
  for (int i = tid; i < 8 * 1056; i += 256) vkl[i] = vg[i];
  __syncthreads();

  const int nl = tid & 31;
  const int hl = tid >> 5;
  const float* vkh = &vkl[hl * 1056];

  const u16* qp = qkv + ((size_t)b * SEQ + n0 + nl) * QKVC + (hh * 8 + hl) * 32;
  float qf[32];
#pragma unroll
  for (int s2 = 0; s2 < 4; ++s2) {
    bf16x8 qv = *(const bf16x8*)(qp + s2 * 8);
#pragma unroll
    for (int j = 0; j < 8; ++j) qf[s2 * 8 + j] = bf2f((u16)qv[j]);
  }

  float num[32];
#pragma unroll
  for (int c = 0; c < 32; ++c) {
    float a = 0.f;
#pragma unroll
    for (int d4 = 0; d4 < 8; ++d4) {
      f32x4 vv = *(const f32x4*)&vkh[c * 32 + d4 * 4];
      a = fmaf(qf[d4 * 4 + 0], vv[0], a);
      a = fmaf(qf[d4 * 4 + 1], vv[1], a);
      a = fmaf(qf[d4 * 4 + 2], vv[2], a);
      a = fmaf(qf[d4 * 4 + 3], vv[3], a);
    }
    num[c] = a;
  }
  float den = 0.f;
#pragma unroll
  for (int d4 = 0; d4 < 8; ++d4) {
    f32x4 vv = *(const f32x4*)&vkh[32 * 32 + d4 * 4];
    den = fmaf(qf[d4 * 4 + 0], vv[0], den);
    den = fmaf(qf[d4 * 4 + 1], vv[1], den);
    den = fmaf(qf[d4 * 4 + 2], vv[2], den);
    den = fmaf(qf[d4 * 4 + 3], vv[3], den);
  }
  const float r = 1.0f / (den + 1e-15f);
#pragma unroll
  for (int c = 0; c < 32; ++c) ob[nl * 256 + hl * 32 + c] = f2bf(num[c] * r);
  __syncthreads();

  u16* pg = pi + ((size_t)b * SEQ + n0) * CH + hh * 256;
  for (int i = tid; i < 1024; i += 256) {
    const int n = i >> 5;
    const int u = i & 31;
    *(bf16x8*)(pg + (size_t)n * CH + u * 8) = *(const bf16x8*)&ob[i * 8];
  }
}

// ---------------------------------------------------------------------------
extern "C" void kernel_launch(void* const* d_in, const int* in_sizes, int n_in,
                              void* d_out, int out_size, void* d_ws, size_t ws_size,
                              hipStream_t stream) {
  const float* x = (const float*)d_in[0];
  const float* qw = (const float*)d_in[1];
  const float* pw = (const float*)d_in[2];
  const float* bias = (const float*)d_in[3];

  char* ws = (char*)d_ws;
  u16* qkv = (u16*)(ws);                      // 65536*1536*2 = 201326592 B
  u16* xb = (u16*)(ws + 201326592);           // 65536*512*2  =  67108864 B
  u16* qwb = (u16*)(ws + 268435456);          // 1536*512*2   =   1572864 B
  u16* pwb = (u16*)(ws + 270008320);          // 512*512*2    =    524288 B
  float* vk = (float*)(ws + 270532608);       // 64*1056*4    =    270336 B
  u16* pi = xb;  // alias: x_bf16 dead after QKV GEMM; reuse for proj_input

  prep_kernel<<<2048, 256, 0, stream>>>(x, qw, pw, xb, qwb, pwb, vk);
  gemm8p_kernel<QKVC, true, false>
      <<<dim3(QKVC / 256, MROWS / 256), 512, 0, stream>>>(xb, qwb, qkv, nullptr);
  vk_kernel<<<NB * NH * 16, 256, 0, stream>>>(qkv, vk);
  vkq_kernel<<<NB * 2 * (SEQ / 32), 256, 0, stream>>>(qkv, vk, pi);
  gemm8p_kernel<CH, false, true>
      <<<dim3(CH / 256, MROWS / 256), 512, 0, stream>>>(pi, pwb, d_out, bias);
}